// Round 1
// baseline (3014.727 us; speedup 1.0000x reference)
//
#include <hip/hip_runtime.h>

// HGCN on MI355X. Key identity: logmap0(expmap0(v)) == v for all vectors
// occurring in this model (EPS clamps only matter for ||v||^2 < 2e-7, and the
// exact-zero case maps to 0 on both paths). The model therefore reduces to:
//   h1 = feat@W1+b1; agg1 = segmean(h1); t1 = sigmoid(agg1)
//   h2 = t1@W2+b2;   agg2 = segmean(h2); t2 = sigmoid(agg2)
//   out = relu(t2@W3+b3)@W4 + b4
// All fp32 (no fp32-input MFMA on CDNA4; GEMM work is tiny vs the scatter).

__device__ __forceinline__ float sigmoidf(float x) {
    return 1.0f / (1.0f + __expf(-x));
}

// Tiled fp32 GEMM: out[N,NCR] = op(in)[N,K] @ W[K,NCR] + bias
// op = sigmoid(x / max(deg,1)) if SIG.  RELU on store if RELU.
// NCP = padded col count (multiple of TC*? , power-of-2 thread layout); cols
// >= NCR are zero-padded in LDS and masked on store.
template<int K, int NCP, int NCR, int TR, int TC, bool SIG, bool RELU>
__global__ __launch_bounds__(256) void gemm_t(
    const float* __restrict__ in, const float* __restrict__ deg,
    const float* __restrict__ W, const float* __restrict__ bias,
    float* __restrict__ out, int N)
{
    constexpr int TX   = NCP / TC;       // thread cols
    constexpr int TY   = 256 / TX;       // thread rows
    constexpr int ROWS = TY * TR;        // rows per block
    constexpr int TSTR = ROWS + 1;       // padded LDS stride (breaks bank conflicts)

    __shared__ alignas(16) float Ws[K * NCP];
    __shared__ alignas(16) float Ts[K * TSTR];   // transposed input tile: Ts[k][r]
    __shared__ float bs[NCP];

    const int tid = threadIdx.x;

    // --- stage W (zero-pad cols >= NCR) ---
    if constexpr (NCP == NCR) {
        constexpr int NW4 = K * NCP / 4;
        const float4* Wg = (const float4*)W;
        float4* Wl = (float4*)Ws;
        #pragma unroll
        for (int i = 0; i < NW4 / 256; i++) Wl[tid + 256 * i] = Wg[tid + 256 * i];
    } else {
        for (int i = tid; i < K * NCP; i += 256) {
            int k = i / NCP, c = i - k * NCP;
            Ws[i] = (c < NCR) ? W[k * NCR + c] : 0.0f;
        }
    }
    for (int i = tid; i < NCP; i += 256) bs[i] = (i < NCR) ? bias[i] : 0.0f;

    // --- stage input tile, transposed, transform fused ---
    const int row0 = blockIdx.x * ROWS;
    constexpr int KC4 = K / 4;
    constexpr int NT4 = ROWS * KC4;
    for (int i = tid; i < NT4; i += 256) {
        int r  = i / KC4;
        int c4 = (i - r * KC4) * 4;
        int row = row0 + r;
        float4 v = make_float4(0.f, 0.f, 0.f, 0.f);
        if (row < N) v = *(const float4*)(in + (size_t)row * K + c4);
        if (SIG) {
            float sc = (row < N) ? (1.0f / fmaxf(deg[row], 1.0f)) : 1.0f;
            v.x = sigmoidf(v.x * sc);
            v.y = sigmoidf(v.y * sc);
            v.z = sigmoidf(v.z * sc);
            v.w = sigmoidf(v.w * sc);
        }
        Ts[(c4 + 0) * TSTR + r] = v.x;
        Ts[(c4 + 1) * TSTR + r] = v.y;
        Ts[(c4 + 2) * TSTR + r] = v.z;
        Ts[(c4 + 3) * TSTR + r] = v.w;
    }
    __syncthreads();

    // --- register-tiled main loop ---
    const int tx = tid % TX, ty = tid / TX;
    const int colb = tx * TC, rowb = ty * TR;
    float acc[TR][TC];
    #pragma unroll
    for (int i = 0; i < TR; i++)
        #pragma unroll
        for (int j = 0; j < TC; j++) acc[i][j] = bs[colb + j];

    for (int k = 0; k < K; k++) {
        float tv[TR];
        #pragma unroll
        for (int i = 0; i < TR; i++) tv[i] = Ts[k * TSTR + rowb + i];
        #pragma unroll
        for (int j = 0; j < TC; j++) {
            float wv = Ws[k * NCP + colb + j];
            #pragma unroll
            for (int i = 0; i < TR; i++) acc[i][j] = fmaf(tv[i], wv, acc[i][j]);
        }
    }

    // --- store ---
    #pragma unroll
    for (int i = 0; i < TR; i++) {
        int row = row0 + rowb + i;
        if (row < N) {
            #pragma unroll
            for (int j = 0; j < TC; j++) {
                int c = colb + j;
                if (c < NCR) {
                    float v = acc[i][j];
                    if (RELU) v = fmaxf(v, 0.f);
                    out[(size_t)row * NCR + c] = v;
                }
            }
        }
    }
}

// Edge scatter: 16 lanes per edge, each handles 4 consecutive floats.
// agg[dst] += h[src]; deg[dst] += 1 (COUNT round only; deg identical both rounds).
template<bool COUNT>
__global__ __launch_bounds__(256) void scatter_t(
    const float* __restrict__ h, const int* __restrict__ src,
    const int* __restrict__ dst, float* __restrict__ agg,
    float* __restrict__ deg, int E)
{
    int t = blockIdx.x * 256 + threadIdx.x;
    int e = t >> 4;
    if (e >= E) return;
    int q = (t & 15) << 2;
    int s = src[e];
    int d = dst[e];
    float4 v = *(const float4*)(h + (size_t)s * 64 + q);
    float* a = agg + (size_t)d * 64 + q;
    atomicAdd(a + 0, v.x);
    atomicAdd(a + 1, v.y);
    atomicAdd(a + 2, v.z);
    atomicAdd(a + 3, v.w);
    if (COUNT && q == 0) atomicAdd(deg + d, 1.0f);
}

extern "C" void kernel_launch(void* const* d_in, const int* in_sizes, int n_in,
                              void* d_out, int out_size, void* d_ws, size_t ws_size,
                              hipStream_t stream)
{
    const float* feat = (const float*)d_in[0];
    const int*   eidx = (const int*)d_in[1];   // [2,E] int32 (harness integer = int)
    const float* W1 = (const float*)d_in[2];
    const float* b1 = (const float*)d_in[3];
    const float* W2 = (const float*)d_in[4];
    const float* b2 = (const float*)d_in[5];
    const float* W3 = (const float*)d_in[6];
    const float* b3 = (const float*)d_in[7];
    const float* W4 = (const float*)d_in[8];
    const float* b4 = (const float*)d_in[9];

    const int N = in_sizes[0] / 64;
    const int E = in_sizes[1] / 2;
    const int* src = eidx;
    const int* dst = eidx + E;

    float* A   = (float*)d_ws;                 // N*64   agg buffer
    float* B   = A  + (size_t)N * 64;          // N*64   h / t buffer
    float* H3  = B  + (size_t)N * 64;          // N*128  hidden MLP buffer
    float* deg = H3 + (size_t)N * 128;         // N      in-degree (float)
    float* out = (float*)d_out;

    hipMemsetAsync(A,   0, (size_t)N * 64 * sizeof(float), stream);
    hipMemsetAsync(deg, 0, (size_t)N * sizeof(float), stream);

    const dim3 blk(256);
    const int g64  = (N + 63) / 64;
    const int g32  = (N + 31) / 32;
    const int gsc  = (int)(((size_t)E * 16 + 255) / 256);

    // h1 = feat@W1+b1
    gemm_t<64, 64, 64, 4, 4, false, false><<<g64, blk, 0, stream>>>(feat, nullptr, W1, b1, B, N);
    // agg1 += h1[src] -> dst ; deg
    scatter_t<true><<<gsc, blk, 0, stream>>>(B, src, dst, A, deg, E);
    // h2 = sigmoid(agg1/deg)@W2+b2
    gemm_t<64, 64, 64, 4, 4, true, false><<<g64, blk, 0, stream>>>(A, deg, W2, b2, B, N);
    // re-zero agg, agg2 += h2[src] -> dst
    hipMemsetAsync(A, 0, (size_t)N * 64 * sizeof(float), stream);
    scatter_t<false><<<gsc, blk, 0, stream>>>(B, src, dst, A, nullptr, E);
    // h3 = relu(sigmoid(agg2/deg)@W3+b3)   [N,128]
    gemm_t<64, 128, 128, 4, 8, true, true><<<g64, blk, 0, stream>>>(A, deg, W3, b3, H3, N);
    // out = h3@W4+b4                       [N,40] (padded to 64 cols in LDS)
    gemm_t<128, 64, 40, 2, 4, false, false><<<g32, blk, 0, stream>>>(H3, nullptr, W4, b4, out, N);
}

// Round 2
// 754.699 us; speedup vs baseline: 3.9946x; 3.9946x over previous
//
#include <hip/hip_runtime.h>

// HGCN on MI355X. logmap0(expmap0(v)) == v for all vectors occurring here,
// so the model reduces to:
//   h1 = feat@W1+b1; t1 = sigmoid(segmean(h1))
//   h2 = t1@W2+b2;   t2 = sigmoid(segmean(h2))
//   out = relu(t2@W3+b3)@W4 + b4
// Round-1 lesson: fp32 atomicAdd scatter is an atomic-throughput wall
// (2x1433us, 16% HBM, VALUBusy 1%). Replace with counting-sort -> CSR ->
// gather; build CSR once, use for both aggregation rounds.

__device__ __forceinline__ float sigmoidf(float x) {
    return 1.0f / (1.0f + __expf(-x));
}

// ---------------- CSR build ----------------

__global__ __launch_bounds__(256) void hist_k(const int* __restrict__ dst,
                                              int* __restrict__ cnt, int E) {
    int e = blockIdx.x * 256 + threadIdx.x;
    if (e < E) atomicAdd(cnt + dst[e], 1);
}

// Single-block exclusive scan of cnt[0..N) -> off[0..N], and cur = off copy.
__global__ __launch_bounds__(1024) void scan_k(const int* __restrict__ cnt,
                                               int* __restrict__ off,
                                               int* __restrict__ cur, int N) {
    __shared__ int sums[1024];
    const int tid = threadIdx.x;
    const int per = (N + 1023) / 1024;
    const int b = tid * per;
    const int e = min(b + per, N);
    int s = 0;
    for (int i = b; i < e; i++) s += cnt[i];
    sums[tid] = s;
    __syncthreads();
    // Hillis-Steele inclusive scan over 1024 partials
    for (int d = 1; d < 1024; d <<= 1) {
        int v = 0;
        if (tid >= d) v = sums[tid - d];
        __syncthreads();
        if (tid >= d) sums[tid] += v;
        __syncthreads();
    }
    int pre = (tid > 0) ? sums[tid - 1] : 0;
    for (int i = b; i < e; i++) {
        off[i] = pre;
        cur[i] = pre;
        pre += cnt[i];
    }
    if (tid == 1023) off[N] = sums[1023];
}

__global__ __launch_bounds__(256) void bucket_k(const int* __restrict__ src,
                                                const int* __restrict__ dst,
                                                int* __restrict__ cur,
                                                int* __restrict__ ssrc, int E) {
    int e = blockIdx.x * 256 + threadIdx.x;
    if (e >= E) return;
    int pos = atomicAdd(cur + dst[e], 1);
    ssrc[pos] = src[e];
}

// ---------------- aggregation (gather) ----------------
// 16 lanes per node, each lane owns 4 consecutive floats of the 64-dim row.
// out[n] = sigmoid( sum_{incoming e} h[src_e] / max(deg,1) )
__global__ __launch_bounds__(256) void agg_k(const float* __restrict__ h,
                                             const int* __restrict__ off,
                                             const int* __restrict__ ssrc,
                                             float* __restrict__ out, int N) {
    int t = blockIdx.x * 256 + threadIdx.x;
    int g = t >> 4;
    if (g >= N) return;
    int q = (t & 15) << 2;
    int beg = off[g], end = off[g + 1];
    float4 acc = make_float4(0.f, 0.f, 0.f, 0.f);
    for (int i = beg; i < end; i++) {
        int s = ssrc[i];
        float4 v = *(const float4*)(h + (size_t)s * 64 + q);
        acc.x += v.x; acc.y += v.y; acc.z += v.z; acc.w += v.w;
    }
    float inv = 1.0f / (float)max(end - beg, 1);
    float4 o;
    o.x = sigmoidf(acc.x * inv);
    o.y = sigmoidf(acc.y * inv);
    o.z = sigmoidf(acc.z * inv);
    o.w = sigmoidf(acc.w * inv);
    *(float4*)(out + (size_t)g * 64 + q) = o;
}

// ---------------- tiled fp32 GEMM ----------------
// out[N,NCR] = in[N,K] @ W[K,NCR] + bias ; optional relu on store.
template<int K, int NCP, int NCR, int TR, int TC, bool RELU>
__global__ __launch_bounds__(256) void gemm_t(
    const float* __restrict__ in, const float* __restrict__ W,
    const float* __restrict__ bias, float* __restrict__ out, int N)
{
    constexpr int TX   = NCP / TC;
    constexpr int TY   = 256 / TX;
    constexpr int ROWS = TY * TR;
    constexpr int TSTR = ROWS + 1;

    __shared__ alignas(16) float Ws[K * NCP];
    __shared__ alignas(16) float Ts[K * TSTR];
    __shared__ float bs[NCP];

    const int tid = threadIdx.x;

    if constexpr (NCP == NCR) {
        constexpr int NW4 = K * NCP / 4;
        const float4* Wg = (const float4*)W;
        float4* Wl = (float4*)Ws;
        #pragma unroll
        for (int i = 0; i < NW4 / 256; i++) Wl[tid + 256 * i] = Wg[tid + 256 * i];
    } else {
        for (int i = tid; i < K * NCP; i += 256) {
            int k = i / NCP, c = i - k * NCP;
            Ws[i] = (c < NCR) ? W[k * NCR + c] : 0.0f;
        }
    }
    for (int i = tid; i < NCP; i += 256) bs[i] = (i < NCR) ? bias[i] : 0.0f;

    const int row0 = blockIdx.x * ROWS;
    constexpr int KC4 = K / 4;
    constexpr int NT4 = ROWS * KC4;
    for (int i = tid; i < NT4; i += 256) {
        int r  = i / KC4;
        int c4 = (i - r * KC4) * 4;
        int row = row0 + r;
        float4 v = make_float4(0.f, 0.f, 0.f, 0.f);
        if (row < N) v = *(const float4*)(in + (size_t)row * K + c4);
        Ts[(c4 + 0) * TSTR + r] = v.x;
        Ts[(c4 + 1) * TSTR + r] = v.y;
        Ts[(c4 + 2) * TSTR + r] = v.z;
        Ts[(c4 + 3) * TSTR + r] = v.w;
    }
    __syncthreads();

    const int tx = tid % TX, ty = tid / TX;
    const int colb = tx * TC, rowb = ty * TR;
    float acc[TR][TC];
    #pragma unroll
    for (int i = 0; i < TR; i++)
        #pragma unroll
        for (int j = 0; j < TC; j++) acc[i][j] = bs[colb + j];

    for (int k = 0; k < K; k++) {
        float tv[TR];
        #pragma unroll
        for (int i = 0; i < TR; i++) tv[i] = Ts[k * TSTR + rowb + i];
        #pragma unroll
        for (int j = 0; j < TC; j++) {
            float wv = Ws[k * NCP + colb + j];
            #pragma unroll
            for (int i = 0; i < TR; i++) acc[i][j] = fmaf(tv[i], wv, acc[i][j]);
        }
    }

    #pragma unroll
    for (int i = 0; i < TR; i++) {
        int row = row0 + rowb + i;
        if (row < N) {
            #pragma unroll
            for (int j = 0; j < TC; j++) {
                int c = colb + j;
                if (c < NCR) {
                    float v = acc[i][j];
                    if (RELU) v = fmaxf(v, 0.f);
                    out[(size_t)row * NCR + c] = v;
                }
            }
        }
    }
}

extern "C" void kernel_launch(void* const* d_in, const int* in_sizes, int n_in,
                              void* d_out, int out_size, void* d_ws, size_t ws_size,
                              hipStream_t stream)
{
    const float* feat = (const float*)d_in[0];
    const int*   eidx = (const int*)d_in[1];
    const float* W1 = (const float*)d_in[2];
    const float* b1 = (const float*)d_in[3];
    const float* W2 = (const float*)d_in[4];
    const float* b2 = (const float*)d_in[5];
    const float* W3 = (const float*)d_in[6];
    const float* b3 = (const float*)d_in[7];
    const float* W4 = (const float*)d_in[8];
    const float* b4 = (const float*)d_in[9];

    const int N = in_sizes[0] / 64;
    const int E = in_sizes[1] / 2;
    const int* src = eidx;
    const int* dst = eidx + E;

    float* A    = (float*)d_ws;                 // N*64  agg / t buffer
    float* B    = A  + (size_t)N * 64;          // N*64  h buffer
    float* H3   = B  + (size_t)N * 64;          // N*128 MLP hidden
    int*   cnt  = (int*)(H3 + (size_t)N * 128); // N
    int*   off  = cnt + N;                      // N+1
    int*   cur  = off + (N + 1);                // N
    int*   ssrc = cur + N;                      // E
    float* out  = (float*)d_out;

    hipMemsetAsync(cnt, 0, (size_t)N * sizeof(int), stream);

    const dim3 blk(256);
    const int gE  = (E + 255) / 256;
    const int g64 = (N + 63) / 64;
    const int g32 = (N + 31) / 32;
    const int gAg = (int)(((size_t)N * 16 + 255) / 256);

    // CSR build (used by both aggregation rounds)
    hist_k<<<gE, blk, 0, stream>>>(dst, cnt, E);
    scan_k<<<1, dim3(1024), 0, stream>>>(cnt, off, cur, N);
    bucket_k<<<gE, blk, 0, stream>>>(src, dst, cur, ssrc, E);

    // h1 = feat@W1+b1
    gemm_t<64, 64, 64, 4, 4, false><<<g64, blk, 0, stream>>>(feat, W1, b1, B, N);
    // t1 = sigmoid(mean_{in-edges} h1[src])
    agg_k<<<gAg, blk, 0, stream>>>(B, off, ssrc, A, N);
    // h2 = t1@W2+b2
    gemm_t<64, 64, 64, 4, 4, false><<<g64, blk, 0, stream>>>(A, W2, b2, B, N);
    // t2 = sigmoid(mean h2[src])
    agg_k<<<gAg, blk, 0, stream>>>(B, off, ssrc, A, N);
    // h3 = relu(t2@W3+b3)  [N,128]
    gemm_t<64, 128, 128, 4, 8, true><<<g64, blk, 0, stream>>>(A, W3, b3, H3, N);
    // out = h3@W4+b4       [N,40]
    gemm_t<128, 64, 40, 2, 4, false><<<g32, blk, 0, stream>>>(H3, W4, b4, out, N);
}

// Round 3
// 525.100 us; speedup vs baseline: 5.7412x; 1.4372x over previous
//
#include <hip/hip_runtime.h>

// HGCN on MI355X. logmap0(expmap0(v)) == v for all vectors occurring here,
// so the model reduces to:
//   h1 = feat@W1+b1; t1 = sigmoid(segmean(h1))
//   h2 = t1@W2+b2;   t2 = sigmoid(segmean(h2))
//   out = relu(t2@W3+b3)@W4 + b4
// R1 lesson: fp32 atomicAdd scatter = atomic wall -> counting-sort CSR + gather.
// R2 lesson: single-block scan = 231us latency wall (0.15% occupancy) ->
//            3-kernel hierarchical scan (~10us).

__device__ __forceinline__ float sigmoidf(float x) {
    return 1.0f / (1.0f + __expf(-x));
}

// ---------------- CSR build ----------------

__global__ __launch_bounds__(256) void hist_k(const int* __restrict__ dst,
                                              int* __restrict__ cnt, int E) {
    int e = blockIdx.x * 256 + threadIdx.x;
    if (e < E) atomicAdd(cnt + dst[e], 1);
}

// Level 1: per-block (1024 elements) reduction of cnt -> bsum[b]
__global__ __launch_bounds__(256) void red_k(const int* __restrict__ cnt,
                                             int* __restrict__ bsum, int N) {
    const int tid = threadIdx.x;
    const int base = blockIdx.x * 1024 + tid * 4;
    int s = 0;
    #pragma unroll
    for (int j = 0; j < 4; j++) {
        int i = base + j;
        if (i < N) s += cnt[i];
    }
    // wave reduce (64 lanes)
    #pragma unroll
    for (int d = 32; d > 0; d >>= 1) s += __shfl_down(s, d, 64);
    __shared__ int wsum[4];
    const int lane = tid & 63, wv = tid >> 6;
    if (lane == 0) wsum[wv] = s;
    __syncthreads();
    if (tid == 0) bsum[blockIdx.x] = wsum[0] + wsum[1] + wsum[2] + wsum[3];
}

// Level 2: single small block scans NB block sums (NB <= 1024) -> exclusive boff
__global__ __launch_bounds__(1024) void scan1_k(const int* __restrict__ bsum,
                                                int* __restrict__ boff,
                                                int* __restrict__ offN,
                                                int NB, int E) {
    __shared__ int sh[1024];
    const int tid = threadIdx.x;
    sh[tid] = (tid < NB) ? bsum[tid] : 0;
    __syncthreads();
    for (int d = 1; d < 1024; d <<= 1) {
        int v = 0;
        if (tid >= d) v = sh[tid - d];
        __syncthreads();
        if (tid >= d) sh[tid] += v;
        __syncthreads();
    }
    if (tid < NB) boff[tid] = (tid > 0) ? sh[tid - 1] : 0;
    if (tid == 0) *offN = E;   // off[N] == total edge count
}

// Level 3: per-block exclusive scan of its 1024-chunk, + boff base.
// Writes off[i] and cur[i] (bucket cursor copy).
__global__ __launch_bounds__(256) void scan2_k(const int* __restrict__ cnt,
                                               const int* __restrict__ boff,
                                               int* __restrict__ off,
                                               int* __restrict__ cur, int N) {
    const int tid = threadIdx.x;
    const int lane = tid & 63, wv = tid >> 6;
    const int base = blockIdx.x * 1024 + tid * 4;
    int v[4];
    #pragma unroll
    for (int j = 0; j < 4; j++) {
        int i = base + j;
        v[j] = (i < N) ? cnt[i] : 0;
    }
    int s = v[0] + v[1] + v[2] + v[3];
    int isc = s;
    #pragma unroll
    for (int d = 1; d < 64; d <<= 1) {
        int t = __shfl_up(isc, d, 64);
        if (lane >= d) isc += t;
    }
    __shared__ int wsum[4];
    if (lane == 63) wsum[wv] = isc;
    __syncthreads();
    int wbase = 0;
    #pragma unroll
    for (int w = 0; w < 4; w++) if (w < wv) wbase += wsum[w];
    int p = boff[blockIdx.x] + wbase + (isc - s);
    #pragma unroll
    for (int j = 0; j < 4; j++) {
        int i = base + j;
        if (i < N) { off[i] = p; cur[i] = p; }
        p += v[j];
    }
}

__global__ __launch_bounds__(256) void bucket_k(const int* __restrict__ src,
                                                const int* __restrict__ dst,
                                                int* __restrict__ cur,
                                                int* __restrict__ ssrc, int E) {
    int e = blockIdx.x * 256 + threadIdx.x;
    if (e >= E) return;
    int pos = atomicAdd(cur + dst[e], 1);
    ssrc[pos] = src[e];
}

// ---------------- aggregation (gather) ----------------
// 16 lanes per node, each lane owns 4 consecutive floats of the 64-dim row.
// out[n] = sigmoid( mean_{incoming e} h[src_e] )
__global__ __launch_bounds__(256) void agg_k(const float* __restrict__ h,
                                             const int* __restrict__ off,
                                             const int* __restrict__ ssrc,
                                             float* __restrict__ out, int N) {
    int t = blockIdx.x * 256 + threadIdx.x;
    int g = t >> 4;
    if (g >= N) return;
    int q = (t & 15) << 2;
    int beg = off[g], end = off[g + 1];
    float4 acc = make_float4(0.f, 0.f, 0.f, 0.f);
    for (int i = beg; i < end; i++) {
        int s = ssrc[i];
        float4 v = *(const float4*)(h + (size_t)s * 64 + q);
        acc.x += v.x; acc.y += v.y; acc.z += v.z; acc.w += v.w;
    }
    float inv = 1.0f / (float)max(end - beg, 1);
    float4 o;
    o.x = sigmoidf(acc.x * inv);
    o.y = sigmoidf(acc.y * inv);
    o.z = sigmoidf(acc.z * inv);
    o.w = sigmoidf(acc.w * inv);
    *(float4*)(out + (size_t)g * 64 + q) = o;
}

// ---------------- tiled fp32 GEMM ----------------
template<int K, int NCP, int NCR, int TR, int TC, bool RELU>
__global__ __launch_bounds__(256) void gemm_t(
    const float* __restrict__ in, const float* __restrict__ W,
    const float* __restrict__ bias, float* __restrict__ out, int N)
{
    constexpr int TX   = NCP / TC;
    constexpr int TY   = 256 / TX;
    constexpr int ROWS = TY * TR;
    constexpr int TSTR = ROWS + 1;

    __shared__ alignas(16) float Ws[K * NCP];
    __shared__ alignas(16) float Ts[K * TSTR];
    __shared__ float bs[NCP];

    const int tid = threadIdx.x;

    if constexpr (NCP == NCR) {
        constexpr int NW4 = K * NCP / 4;
        const float4* Wg = (const float4*)W;
        float4* Wl = (float4*)Ws;
        #pragma unroll
        for (int i = 0; i < NW4 / 256; i++) Wl[tid + 256 * i] = Wg[tid + 256 * i];
    } else {
        for (int i = tid; i < K * NCP; i += 256) {
            int k = i / NCP, c = i - k * NCP;
            Ws[i] = (c < NCR) ? W[k * NCR + c] : 0.0f;
        }
    }
    for (int i = tid; i < NCP; i += 256) bs[i] = (i < NCR) ? bias[i] : 0.0f;

    const int row0 = blockIdx.x * ROWS;
    constexpr int KC4 = K / 4;
    constexpr int NT4 = ROWS * KC4;
    for (int i = tid; i < NT4; i += 256) {
        int r  = i / KC4;
        int c4 = (i - r * KC4) * 4;
        int row = row0 + r;
        float4 v = make_float4(0.f, 0.f, 0.f, 0.f);
        if (row < N) v = *(const float4*)(in + (size_t)row * K + c4);
        Ts[(c4 + 0) * TSTR + r] = v.x;
        Ts[(c4 + 1) * TSTR + r] = v.y;
        Ts[(c4 + 2) * TSTR + r] = v.z;
        Ts[(c4 + 3) * TSTR + r] = v.w;
    }
    __syncthreads();

    const int tx = tid % TX, ty = tid / TX;
    const int colb = tx * TC, rowb = ty * TR;
    float acc[TR][TC];
    #pragma unroll
    for (int i = 0; i < TR; i++)
        #pragma unroll
        for (int j = 0; j < TC; j++) acc[i][j] = bs[colb + j];

    for (int k = 0; k < K; k++) {
        float tv[TR];
        #pragma unroll
        for (int i = 0; i < TR; i++) tv[i] = Ts[k * TSTR + rowb + i];
        #pragma unroll
        for (int j = 0; j < TC; j++) {
            float wv = Ws[k * NCP + colb + j];
            #pragma unroll
            for (int i = 0; i < TR; i++) acc[i][j] = fmaf(tv[i], wv, acc[i][j]);
        }
    }

    #pragma unroll
    for (int i = 0; i < TR; i++) {
        int row = row0 + rowb + i;
        if (row < N) {
            #pragma unroll
            for (int j = 0; j < TC; j++) {
                int c = colb + j;
                if (c < NCR) {
                    float v = acc[i][j];
                    if (RELU) v = fmaxf(v, 0.f);
                    out[(size_t)row * NCR + c] = v;
                }
            }
        }
    }
}

extern "C" void kernel_launch(void* const* d_in, const int* in_sizes, int n_in,
                              void* d_out, int out_size, void* d_ws, size_t ws_size,
                              hipStream_t stream)
{
    const float* feat = (const float*)d_in[0];
    const int*   eidx = (const int*)d_in[1];
    const float* W1 = (const float*)d_in[2];
    const float* b1 = (const float*)d_in[3];
    const float* W2 = (const float*)d_in[4];
    const float* b2 = (const float*)d_in[5];
    const float* W3 = (const float*)d_in[6];
    const float* b3 = (const float*)d_in[7];
    const float* W4 = (const float*)d_in[8];
    const float* b4 = (const float*)d_in[9];

    const int N = in_sizes[0] / 64;
    const int E = in_sizes[1] / 2;
    const int* src = eidx;
    const int* dst = eidx + E;

    const int NB = (N + 1023) / 1024;          // scan chunks

    float* A    = (float*)d_ws;                 // N*64  agg / t buffer
    float* B    = A  + (size_t)N * 64;          // N*64  h buffer
    float* H3   = B  + (size_t)N * 64;          // N*128 MLP hidden
    int*   cnt  = (int*)(H3 + (size_t)N * 128); // N
    int*   off  = cnt + N;                      // N+1
    int*   cur  = off + (N + 1);                // N
    int*   ssrc = cur + N;                      // E
    int*   bsum = ssrc + E;                     // NB
    int*   boff = bsum + NB;                    // NB
    float* out  = (float*)d_out;

    hipMemsetAsync(cnt, 0, (size_t)N * sizeof(int), stream);

    const dim3 blk(256);
    const int gE  = (E + 255) / 256;
    const int g64 = (N + 63) / 64;
    const int g32 = (N + 31) / 32;
    const int gAg = (int)(((size_t)N * 16 + 255) / 256);

    // CSR build (used by both aggregation rounds)
    hist_k<<<gE, blk, 0, stream>>>(dst, cnt, E);
    red_k<<<NB, blk, 0, stream>>>(cnt, bsum, N);
    scan1_k<<<1, dim3(1024), 0, stream>>>(bsum, boff, off + N, NB, E);
    scan2_k<<<NB, blk, 0, stream>>>(cnt, boff, off, cur, N);
    bucket_k<<<gE, blk, 0, stream>>>(src, dst, cur, ssrc, E);

    // h1 = feat@W1+b1
    gemm_t<64, 64, 64, 4, 4, false><<<g64, blk, 0, stream>>>(feat, W1, b1, B, N);
    // t1 = sigmoid(mean h1[src])
    agg_k<<<gAg, blk, 0, stream>>>(B, off, ssrc, A, N);
    // h2 = t1@W2+b2
    gemm_t<64, 64, 64, 4, 4, false><<<g64, blk, 0, stream>>>(A, W2, b2, B, N);
    // t2 = sigmoid(mean h2[src])
    agg_k<<<gAg, blk, 0, stream>>>(B, off, ssrc, A, N);
    // h3 = relu(t2@W3+b3)  [N,128]
    gemm_t<64, 128, 128, 4, 8, true><<<g64, blk, 0, stream>>>(A, W3, b3, H3, N);
    // out = h3@W4+b4       [N,40]
    gemm_t<128, 64, 40, 2, 4, false><<<g32, blk, 0, stream>>>(H3, W4, b4, out, N);
}